// Round 1
// baseline (1205.771 us; speedup 1.0000x reference)
//
#include <hip/hip_runtime.h>

// GMMNet: B=4,S=8,C=3,H=W=384,K=5. Entirely pointwise per pixel; scan over S
// carries per-pixel state (pi[5], mu[15], sigma[5]) in registers.
// One thread per pixel, one kernel launch, s-loop in-thread.

namespace {

constexpr int Kk = 5;
constexpr int Cc = 3;
constexpr int CKc = 15;   // C*K
constexpr int Bb = 4;
constexpr int Ss = 8;
constexpr int HWc = 384 * 384;

__device__ __forceinline__ float rcpf(float x) { return __builtin_amdgcn_rcpf(x); }
__device__ __forceinline__ float rsqf(float x) { return __builtin_amdgcn_rsqf(x); }
__device__ __forceinline__ float sigm(float x) { return rcpf(1.0f + __expf(-x)); }
__device__ __forceinline__ float relu(float x) { return fmaxf(x, 0.0f); }

__global__ __launch_bounds__(256) void gmm_seq_kernel(
    const float* __restrict__ frames,
    const float* __restrict__ mu0,
    const float* __restrict__ pw1, const float* __restrict__ pb1,
    const float* __restrict__ pw2, const float* __restrict__ pb2,
    const float* __restrict__ mw1, const float* __restrict__ mb1,
    const float* __restrict__ mw2, const float* __restrict__ mb2,
    const float* __restrict__ sw1, const float* __restrict__ sb1,
    const float* __restrict__ sw2, const float* __restrict__ sb2,
    const float* __restrict__ gw1, const float* __restrict__ gb1,
    const float* __restrict__ gw2, const float* __restrict__ gb2,
    float* __restrict__ out)
{
    const int tid = blockIdx.x * blockDim.x + threadIdx.x;
    if (tid >= Bb * HWc) return;
    const int b  = tid / HWc;
    const int hw = tid - b * HWc;

    const float TWOPI = 6.2831853071795864769f;

    // Per-pixel carried state, in registers.
    float pi[Kk], mu[CKc], sg[Kk];
#pragma unroll
    for (int k = 0; k < Kk; k++) { pi[k] = 0.2f; sg[k] = 1.0f; }
    {
        const float* mp = mu0 + (size_t)b * CKc * HWc + hw;
#pragma unroll
        for (int j = 0; j < CKc; j++) mu[j] = mp[(size_t)j * HWc];
    }

    // Keep s-loop rolled: body is ~1k instrs; unrolled x8 would blow I-cache.
#pragma unroll 1
    for (int s = 0; s < Ss; s++) {
        float x[Cc];
        const float* fp = frames + ((size_t)(b * Ss + s) * Cc) * HWc + hw;
#pragma unroll
        for (int c = 0; c < Cc; c++) x[c] = fp[(size_t)c * HWc];

        // ---- density(x; mu, sigma) ----
        float dens[Kk];
#pragma unroll
        for (int k = 0; k < Kk; k++) {
            float s2 = sg[k] * sg[k];
            float d0 = x[0] - mu[k * Cc + 0];
            float d1 = x[1] - mu[k * Cc + 1];
            float d2 = x[2] - mu[k * Cc + 2];
            float dist = d0 * d0 + d1 * d1 + d2 * d2;
            float r = rsqf(TWOPI * s2);
            float coef = r * r * r;               // (2*pi*s2)^{-3/2}
            dens[k] = coef * __expf(-0.5f * dist * rcpf(s2));
        }

        float alpha[Kk], rho[Kk];
#pragma unroll
        for (int k = 0; k < Kk; k++) { alpha[k] = pi[k] * dens[k]; rho[k] = alpha[k] * dens[k]; }

        // ---- pi MLP (10 -> 5 -> 5) + softmax over K ----
        float piN[Kk];
        {
            float in[2 * Kk];
#pragma unroll
            for (int k = 0; k < Kk; k++) { in[k] = pi[k]; in[Kk + k] = alpha[k]; }
            float h[Kk];
#pragma unroll
            for (int j = 0; j < Kk; j++) {
                float a = pb1[j];
#pragma unroll
                for (int i = 0; i < 2 * Kk; i++) a = fmaf(pw1[j * 2 * Kk + i], in[i], a);
                h[j] = relu(a);
            }
            float o[Kk];
            float m = -1e30f;
#pragma unroll
            for (int j = 0; j < Kk; j++) {
                float a = pb2[j];
#pragma unroll
                for (int i = 0; i < Kk; i++) a = fmaf(pw2[j * Kk + i], h[i], a);
                o[j] = a; m = fmaxf(m, a);
            }
            float sum = 0.0f;
#pragma unroll
            for (int j = 0; j < Kk; j++) { o[j] = __expf(o[j] - m); sum += o[j]; }
            float r = rcpf(sum);
#pragma unroll
            for (int j = 0; j < Kk; j++) piN[j] = o[j] * r;
        }

        // ---- mu MLP (23 -> 15 -> 15), sigmoid ----
        float muN[CKc];
        {
            float in[23];
            in[0] = x[0]; in[1] = x[1]; in[2] = x[2];
#pragma unroll
            for (int j = 0; j < CKc; j++) in[3 + j] = mu[j];
#pragma unroll
            for (int k = 0; k < Kk; k++) in[18 + k] = rho[k];
            float h[CKc];
#pragma unroll
            for (int j = 0; j < CKc; j++) {
                float a = mb1[j];
#pragma unroll
                for (int i = 0; i < 23; i++) a = fmaf(mw1[j * 23 + i], in[i], a);
                h[j] = relu(a);
            }
#pragma unroll
            for (int j = 0; j < CKc; j++) {
                float a = mb2[j];
#pragma unroll
                for (int i = 0; i < CKc; i++) a = fmaf(mw2[j * CKc + i], h[i], a);
                muN[j] = sigm(a);
            }
        }

        // ---- sigma MLP (23 -> 5 -> 5), exp(relu(.)) ----
        float sgN[Kk];
        {
            float in[23];
            in[0] = x[0]; in[1] = x[1]; in[2] = x[2];
#pragma unroll
            for (int j = 0; j < CKc; j++) in[3 + j] = muN[j];
#pragma unroll
            for (int k = 0; k < Kk; k++) in[18 + k] = rho[k];
            float h[Kk];
#pragma unroll
            for (int j = 0; j < Kk; j++) {
                float a = sb1[j];
#pragma unroll
                for (int i = 0; i < 23; i++) a = fmaf(sw1[j * 23 + i], in[i], a);
                h[j] = relu(a);
            }
#pragma unroll
            for (int j = 0; j < Kk; j++) {
                float a = sb2[j];
#pragma unroll
                for (int i = 0; i < Kk; i++) a = fmaf(sw2[j * Kk + i], h[i], a);
                sgN[j] = __expf(relu(a));
            }
        }

        // ---- dens2(x; muN, sgN), gamma MLP (5 -> 5 -> 1), sigmoid ----
        float gin[Kk];
#pragma unroll
        for (int k = 0; k < Kk; k++) {
            float s2 = sgN[k] * sgN[k];
            float d0 = x[0] - muN[k * Cc + 0];
            float d1 = x[1] - muN[k * Cc + 1];
            float d2 = x[2] - muN[k * Cc + 2];
            float dist = d0 * d0 + d1 * d1 + d2 * d2;
            float r = rsqf(TWOPI * s2);
            float coef = r * r * r;
            gin[k] = piN[k] * (coef * __expf(-0.5f * dist * rcpf(s2)));
        }
        {
            float h[Kk];
#pragma unroll
            for (int j = 0; j < Kk; j++) {
                float a = gb1[j];
#pragma unroll
                for (int i = 0; i < Kk; i++) a = fmaf(gw1[j * Kk + i], gin[i], a);
                h[j] = relu(a);
            }
            float go = gb2[0];
#pragma unroll
            for (int i = 0; i < Kk; i++) go = fmaf(gw2[i], h[i], go);
            out[(size_t)(b * Ss + s) * HWc + hw] = sigm(go);
        }

        // ---- carry state ----
#pragma unroll
        for (int k = 0; k < Kk; k++) { pi[k] = piN[k]; sg[k] = sgN[k]; }
#pragma unroll
        for (int j = 0; j < CKc; j++) mu[j] = muN[j];
    }
}

} // namespace

extern "C" void kernel_launch(void* const* d_in, const int* in_sizes, int n_in,
                              void* d_out, int out_size, void* d_ws, size_t ws_size,
                              hipStream_t stream) {
    // setup_inputs order:
    // 0 frames, 1 targets(unused), 2 mu0,
    // 3 pi_w1, 4 pi_b1, 5 pi_w2, 6 pi_b2,
    // 7 mu_w1, 8 mu_b1, 9 mu_w2, 10 mu_b2,
    // 11 sg_w1, 12 sg_b1, 13 sg_w2, 14 sg_b2,
    // 15 ga_w1, 16 ga_b1, 17 ga_w2, 18 ga_b2
    const float* frames = (const float*)d_in[0];
    const float* mu0    = (const float*)d_in[2];
    const float* pw1 = (const float*)d_in[3];
    const float* pb1 = (const float*)d_in[4];
    const float* pw2 = (const float*)d_in[5];
    const float* pb2 = (const float*)d_in[6];
    const float* mw1 = (const float*)d_in[7];
    const float* mb1 = (const float*)d_in[8];
    const float* mw2 = (const float*)d_in[9];
    const float* mb2 = (const float*)d_in[10];
    const float* sw1 = (const float*)d_in[11];
    const float* sb1 = (const float*)d_in[12];
    const float* sw2 = (const float*)d_in[13];
    const float* sb2 = (const float*)d_in[14];
    const float* gw1 = (const float*)d_in[15];
    const float* gb1 = (const float*)d_in[16];
    const float* gw2 = (const float*)d_in[17];
    const float* gb2 = (const float*)d_in[18];
    float* out = (float*)d_out;

    const int total = Bb * HWc;          // 589,824 pixels
    const int block = 256;
    const int grid = (total + block - 1) / block;   // 2304 blocks

    gmm_seq_kernel<<<grid, block, 0, stream>>>(
        frames, mu0,
        pw1, pb1, pw2, pb2,
        mw1, mb1, mw2, mb2,
        sw1, sb1, sw2, sb2,
        gw1, gb1, gw2, gb2,
        out);
}

// Round 2
// 610.147 us; speedup vs baseline: 1.9762x; 1.9762x over previous
//
#include <hip/hip_runtime.h>

// GMMNet: B=4,S=8,C=3,H=W=384,K=5. Pointwise per pixel; scan over S carries
// per-pixel state (pi[5], mu[15], rinv[5]=1/sigma) in registers.
// Round 2 change: all 871 weight floats staged into LDS once per block
// (padded rows -> ds_read_b128-mergeable, broadcast reads, no SGPR-budget
// reload serialization in the s-loop). Also carry rinv instead of sigma:
// rinv_new = exp(-relu(a)) removes all rcp/rsq in the density evals.

namespace {

constexpr int Kk = 5;
constexpr int Cc = 3;
constexpr int CKc = 15;   // C*K
constexpr int Bb = 4;
constexpr int Ss = 8;
constexpr int HWc = 384 * 384;

// LDS layout (float offsets); all matrix bases and pitches are %4==0 so
// consecutive constant-offset reads can merge into ds_read_b128.
constexpr int PW1 = 0,   PP1 = 12;  // pi_w1  5x10, pitch 12 -> 60
constexpr int PB1 = 60;             // pi_b1  5 (pad 8)
constexpr int PW2 = 68,  PP2 = 8;   // pi_w2  5x5,  pitch 8  -> 40
constexpr int PB2 = 108;            // pi_b2  5 (pad 8)
constexpr int MW1 = 116, MP1 = 24;  // mu_w1  15x23, pitch 24 -> 360
constexpr int MB1 = 476;            // mu_b1  15 (pad 16)
constexpr int MW2 = 492, MP2 = 16;  // mu_w2  15x15, pitch 16 -> 240
constexpr int MB2 = 732;            // mu_b2  15 (pad 16)
constexpr int SW1 = 748, SP1 = 24;  // sg_w1  5x23, pitch 24 -> 120
constexpr int SB1 = 868;            // sg_b1  5 (pad 8)
constexpr int SW2 = 876, SP2 = 8;   // sg_w2  5x5 -> 40
constexpr int SB2 = 916;            // sg_b2  5 (pad 8)
constexpr int GW1 = 924, GP1 = 8;   // ga_w1  5x5 -> 40
constexpr int GB1 = 964;            // ga_b1  5 (pad 8)
constexpr int GW2 = 972;            // ga_w2  5 (pad 8)
constexpr int GB2 = 980;            // ga_b2  1 (pad 4)
constexpr int WTOT = 984;           // 3936 B

__device__ __forceinline__ float rcpf(float x) { return __builtin_amdgcn_rcpf(x); }
__device__ __forceinline__ float sigm(float x) { return rcpf(1.0f + __expf(-x)); }
__device__ __forceinline__ float relu(float x) { return fmaxf(x, 0.0f); }

__device__ __forceinline__ void stage(float* W, int dst, const float* __restrict__ src,
                                      int rows, int cols, int pitch, int tid) {
    for (int t = tid; t < rows * pitch; t += 256) {
        int r = t / pitch, c = t - r * pitch;
        W[dst + t] = (c < cols) ? src[r * cols + c] : 0.0f;
    }
}

__global__ __launch_bounds__(256) void gmm_seq_kernel(
    const float* __restrict__ frames,
    const float* __restrict__ mu0,
    const float* __restrict__ pw1, const float* __restrict__ pb1,
    const float* __restrict__ pw2, const float* __restrict__ pb2,
    const float* __restrict__ mw1, const float* __restrict__ mb1,
    const float* __restrict__ mw2, const float* __restrict__ mb2,
    const float* __restrict__ sw1, const float* __restrict__ sb1,
    const float* __restrict__ sw2, const float* __restrict__ sb2,
    const float* __restrict__ gw1, const float* __restrict__ gb1,
    const float* __restrict__ gw2, const float* __restrict__ gb2,
    float* __restrict__ out)
{
    __shared__ float sW[WTOT];
    {
        const int t = threadIdx.x;
        stage(sW, PW1, pw1, Kk, 2 * Kk, PP1, t);
        stage(sW, PB1, pb1, 1, Kk, 8, t);
        stage(sW, PW2, pw2, Kk, Kk, PP2, t);
        stage(sW, PB2, pb2, 1, Kk, 8, t);
        stage(sW, MW1, mw1, CKc, 23, MP1, t);
        stage(sW, MB1, mb1, 1, CKc, 16, t);
        stage(sW, MW2, mw2, CKc, CKc, MP2, t);
        stage(sW, MB2, mb2, 1, CKc, 16, t);
        stage(sW, SW1, sw1, Kk, 23, SP1, t);
        stage(sW, SB1, sb1, 1, Kk, 8, t);
        stage(sW, SW2, sw2, Kk, Kk, SP2, t);
        stage(sW, SB2, sb2, 1, Kk, 8, t);
        stage(sW, GW1, gw1, Kk, Kk, GP1, t);
        stage(sW, GB1, gb1, 1, Kk, 8, t);
        stage(sW, GW2, gw2, 1, Kk, 8, t);
        stage(sW, GB2, gb2, 1, 1, 4, t);
    }
    __syncthreads();

    const int tid = blockIdx.x * blockDim.x + threadIdx.x;
    const int b  = tid / HWc;
    const int hw = tid - b * HWc;

    const float C0 = 0.06349363593424097f;   // (2*pi)^{-3/2}

    // Per-pixel carried state, in registers.
    float pi[Kk], mu[CKc], rinv[Kk];         // rinv = 1/sigma
#pragma unroll
    for (int k = 0; k < Kk; k++) { pi[k] = 0.2f; rinv[k] = 1.0f; }
    {
        const float* mp = mu0 + (size_t)b * CKc * HWc + hw;
#pragma unroll
        for (int j = 0; j < CKc; j++) mu[j] = mp[(size_t)j * HWc];
    }

#pragma unroll 1
    for (int s = 0; s < Ss; s++) {
        float x[Cc];
        const float* fp = frames + ((size_t)(b * Ss + s) * Cc) * HWc + hw;
#pragma unroll
        for (int c = 0; c < Cc; c++) x[c] = fp[(size_t)c * HWc];

        // ---- density(x; mu, 1/rinv) ----
        float dens[Kk];
#pragma unroll
        for (int k = 0; k < Kk; k++) {
            float inv_s2 = rinv[k] * rinv[k];
            float d0 = x[0] - mu[k * Cc + 0];
            float d1 = x[1] - mu[k * Cc + 1];
            float d2 = x[2] - mu[k * Cc + 2];
            float dist = d0 * d0 + d1 * d1 + d2 * d2;
            float coef = C0 * inv_s2 * rinv[k];            // C0 * rinv^3
            dens[k] = coef * __expf(-0.5f * dist * inv_s2);
        }

        float alpha[Kk], rho[Kk];
#pragma unroll
        for (int k = 0; k < Kk; k++) { alpha[k] = pi[k] * dens[k]; rho[k] = alpha[k] * dens[k]; }

        // ---- pi MLP (10 -> 5 -> 5) + softmax over K ----
        float piN[Kk];
        {
            float in[2 * Kk];
#pragma unroll
            for (int k = 0; k < Kk; k++) { in[k] = pi[k]; in[Kk + k] = alpha[k]; }
            float h[Kk];
#pragma unroll
            for (int j = 0; j < Kk; j++) {
                float a = sW[PB1 + j];
#pragma unroll
                for (int i = 0; i < 2 * Kk; i++) a = fmaf(sW[PW1 + j * PP1 + i], in[i], a);
                h[j] = relu(a);
            }
            float o[Kk];
            float m = -1e30f;
#pragma unroll
            for (int j = 0; j < Kk; j++) {
                float a = sW[PB2 + j];
#pragma unroll
                for (int i = 0; i < Kk; i++) a = fmaf(sW[PW2 + j * PP2 + i], h[i], a);
                o[j] = a; m = fmaxf(m, a);
            }
            float sum = 0.0f;
#pragma unroll
            for (int j = 0; j < Kk; j++) { o[j] = __expf(o[j] - m); sum += o[j]; }
            float r = rcpf(sum);
#pragma unroll
            for (int j = 0; j < Kk; j++) piN[j] = o[j] * r;
        }

        // ---- mu MLP (23 -> 15 -> 15), sigmoid ----
        float muN[CKc];
        {
            float in[23];
            in[0] = x[0]; in[1] = x[1]; in[2] = x[2];
#pragma unroll
            for (int j = 0; j < CKc; j++) in[3 + j] = mu[j];
#pragma unroll
            for (int k = 0; k < Kk; k++) in[18 + k] = rho[k];
            float h[CKc];
#pragma unroll
            for (int j = 0; j < CKc; j++) {
                float a = sW[MB1 + j];
#pragma unroll
                for (int i = 0; i < 23; i++) a = fmaf(sW[MW1 + j * MP1 + i], in[i], a);
                h[j] = relu(a);
            }
#pragma unroll
            for (int j = 0; j < CKc; j++) {
                float a = sW[MB2 + j];
#pragma unroll
                for (int i = 0; i < CKc; i++) a = fmaf(sW[MW2 + j * MP2 + i], h[i], a);
                muN[j] = sigm(a);
            }
        }

        // ---- sigma MLP (23 -> 5 -> 5): carry rinvN = exp(-relu(a)) = 1/sigma_new ----
        float rinvN[Kk];
        {
            float in[23];
            in[0] = x[0]; in[1] = x[1]; in[2] = x[2];
#pragma unroll
            for (int j = 0; j < CKc; j++) in[3 + j] = muN[j];
#pragma unroll
            for (int k = 0; k < Kk; k++) in[18 + k] = rho[k];
            float h[Kk];
#pragma unroll
            for (int j = 0; j < Kk; j++) {
                float a = sW[SB1 + j];
#pragma unroll
                for (int i = 0; i < 23; i++) a = fmaf(sW[SW1 + j * SP1 + i], in[i], a);
                h[j] = relu(a);
            }
#pragma unroll
            for (int j = 0; j < Kk; j++) {
                float a = sW[SB2 + j];
#pragma unroll
                for (int i = 0; i < Kk; i++) a = fmaf(sW[SW2 + j * SP2 + i], h[i], a);
                rinvN[j] = __expf(-relu(a));
            }
        }

        // ---- dens2(x; muN, 1/rinvN), gamma MLP (5 -> 5 -> 1), sigmoid ----
        float gin[Kk];
#pragma unroll
        for (int k = 0; k < Kk; k++) {
            float inv_s2 = rinvN[k] * rinvN[k];
            float d0 = x[0] - muN[k * Cc + 0];
            float d1 = x[1] - muN[k * Cc + 1];
            float d2 = x[2] - muN[k * Cc + 2];
            float dist = d0 * d0 + d1 * d1 + d2 * d2;
            float coef = C0 * inv_s2 * rinvN[k];
            gin[k] = piN[k] * (coef * __expf(-0.5f * dist * inv_s2));
        }
        {
            float h[Kk];
#pragma unroll
            for (int j = 0; j < Kk; j++) {
                float a = sW[GB1 + j];
#pragma unroll
                for (int i = 0; i < Kk; i++) a = fmaf(sW[GW1 + j * GP1 + i], gin[i], a);
                h[j] = relu(a);
            }
            float go = sW[GB2];
#pragma unroll
            for (int i = 0; i < Kk; i++) go = fmaf(sW[GW2 + i], h[i], go);
            out[(size_t)(b * Ss + s) * HWc + hw] = sigm(go);
        }

        // ---- carry state ----
#pragma unroll
        for (int k = 0; k < Kk; k++) { pi[k] = piN[k]; rinv[k] = rinvN[k]; }
#pragma unroll
        for (int j = 0; j < CKc; j++) mu[j] = muN[j];
    }
}

} // namespace

extern "C" void kernel_launch(void* const* d_in, const int* in_sizes, int n_in,
                              void* d_out, int out_size, void* d_ws, size_t ws_size,
                              hipStream_t stream) {
    const float* frames = (const float*)d_in[0];
    const float* mu0    = (const float*)d_in[2];
    const float* pw1 = (const float*)d_in[3];
    const float* pb1 = (const float*)d_in[4];
    const float* pw2 = (const float*)d_in[5];
    const float* pb2 = (const float*)d_in[6];
    const float* mw1 = (const float*)d_in[7];
    const float* mb1 = (const float*)d_in[8];
    const float* mw2 = (const float*)d_in[9];
    const float* mb2 = (const float*)d_in[10];
    const float* sw1 = (const float*)d_in[11];
    const float* sb1 = (const float*)d_in[12];
    const float* sw2 = (const float*)d_in[13];
    const float* sb2 = (const float*)d_in[14];
    const float* gw1 = (const float*)d_in[15];
    const float* gb1 = (const float*)d_in[16];
    const float* gw2 = (const float*)d_in[17];
    const float* gb2 = (const float*)d_in[18];
    float* out = (float*)d_out;

    const int total = Bb * HWc;          // 589,824 pixels
    const int block = 256;
    const int grid = (total + block - 1) / block;   // 2304 blocks

    gmm_seq_kernel<<<grid, block, 0, stream>>>(
        frames, mu0,
        pw1, pb1, pw2, pb2,
        mw1, mb1, mw2, mb2,
        sw1, sb1, sw2, sb2,
        gw1, gb1, gw2, gb2,
        out);
}